// Round 1
// baseline (502.542 us; speedup 1.0000x reference)
//
#include <hip/hip_runtime.h>

#define NUM_USERS 100000
#define NUM_ITEMS 100000
#define EMB_DIM   128
#define NUM_EDGES 600000
#define NN        200000   // N_NODES

#define SCAN_B  256
#define SCAN_NB ((NN + SCAN_B - 1) / SCAN_B)   // 782

// ---------- degree count (in-degree over col) ----------
__global__ void k_count(const int* __restrict__ col, int* __restrict__ deg) {
    int e = blockIdx.x * blockDim.x + threadIdx.x;
    if (e < NUM_EDGES) atomicAdd(&deg[col[e]], 1);
}

// ---------- deg_inv_sqrt ----------
__global__ void k_dis(const int* __restrict__ deg, float* __restrict__ dis) {
    int i = blockIdx.x * blockDim.x + threadIdx.x;
    if (i < NN) {
        int d = deg[i];
        dis[i] = (d > 0) ? 1.0f / sqrtf((float)d) : 0.0f;
    }
}

// ---------- exclusive scan of deg -> row_ptr (3 kernels) ----------
__global__ void k_scan1(const int* __restrict__ deg, int* __restrict__ rp,
                        int* __restrict__ bsum) {
    __shared__ int s[SCAN_B];
    int tid = threadIdx.x;
    int i = blockIdx.x * SCAN_B + tid;
    int v = (i < NN) ? deg[i] : 0;
    s[tid] = v;
    __syncthreads();
    for (int off = 1; off < SCAN_B; off <<= 1) {
        int t = (tid >= off) ? s[tid - off] : 0;
        __syncthreads();
        s[tid] += t;
        __syncthreads();
    }
    if (i < NN) rp[i] = s[tid] - v;           // exclusive within block
    if (tid == SCAN_B - 1) bsum[blockIdx.x] = s[tid];
}

__global__ void k_scan2(int* __restrict__ bsum) {
    __shared__ int s[1024];
    int tid = threadIdx.x;
    int v = (tid < SCAN_NB) ? bsum[tid] : 0;
    s[tid] = v;
    __syncthreads();
    for (int off = 1; off < 1024; off <<= 1) {
        int t = (tid >= off) ? s[tid - off] : 0;
        __syncthreads();
        s[tid] += t;
        __syncthreads();
    }
    if (tid < SCAN_NB) bsum[tid] = s[tid] - v;  // exclusive
}

__global__ void k_scan3(int* __restrict__ rp, const int* __restrict__ bsum) {
    int i = blockIdx.x * SCAN_B + threadIdx.x;
    if (i < NN) rp[i] += bsum[blockIdx.x];
    if (i == 0) rp[NN] = NUM_EDGES;
}

// ---------- CSR fill (by destination node) ----------
__global__ void k_fill(const int* __restrict__ row, const int* __restrict__ col,
                       const float* __restrict__ dis, const int* __restrict__ rp,
                       int* __restrict__ cursor, int* __restrict__ csr_src,
                       float* __restrict__ csr_coef) {
    int e = blockIdx.x * blockDim.x + threadIdx.x;
    if (e >= NUM_EDGES) return;
    int r = row[e], c = col[e];
    int p = rp[c] + atomicAdd(&cursor[c], 1);
    csr_src[p]  = r;
    csr_coef[p] = dis[r] * dis[c];
}

// ---------- one propagation layer, one wave per destination node ----------
// MODE 0: y = A x   (x == emb);  xn = y;  out = x + y
// MODE 1: y = A x;               xn = y;  out += y
// MODE 2: y = A x;                        out = (out + y) * 0.25
template <int MODE>
__global__ void k_layer(const float* __restrict__ x, const int* __restrict__ rp,
                        const int* __restrict__ src, const float* __restrict__ coef,
                        float* __restrict__ xn, float* __restrict__ out) {
    int w    = (int)((blockIdx.x * blockDim.x + threadIdx.x) >> 6);
    int lane = threadIdx.x & 63;
    if (w >= NN) return;
    int beg = rp[w], end = rp[w + 1];
    float ax = 0.0f, ay = 0.0f;
    const long bd = (long)lane * 2;
    for (int k = beg; k < end; ++k) {
        int   s = src[k];
        float c = coef[k];
        const float2 v = *reinterpret_cast<const float2*>(x + (long)s * EMB_DIM + bd);
        ax += c * v.x;
        ay += c * v.y;
    }
    const long o = (long)w * EMB_DIM + bd;
    if (MODE == 0) {
        *reinterpret_cast<float2*>(xn + o) = make_float2(ax, ay);
        const float2 e = *reinterpret_cast<const float2*>(x + o);
        *reinterpret_cast<float2*>(out + o) = make_float2(e.x + ax, e.y + ay);
    } else if (MODE == 1) {
        *reinterpret_cast<float2*>(xn + o) = make_float2(ax, ay);
        const float2 t = *reinterpret_cast<const float2*>(out + o);
        *reinterpret_cast<float2*>(out + o) = make_float2(t.x + ax, t.y + ay);
    } else {
        const float2 t = *reinterpret_cast<const float2*>(out + o);
        *reinterpret_cast<float2*>(out + o) = make_float2((t.x + ax) * 0.25f, (t.y + ay) * 0.25f);
    }
}

extern "C" void kernel_launch(void* const* d_in, const int* in_sizes, int n_in,
                              void* d_out, int out_size, void* d_ws, size_t ws_size,
                              hipStream_t stream) {
    const int*   edges = (const int*)d_in[0];
    const int*   row   = edges;               // edge_index[0]
    const int*   col   = edges + NUM_EDGES;   // edge_index[1]
    const float* emb   = (const float*)d_in[1];
    float*       out   = (float*)d_out;

    char*  ws  = (char*)d_ws;
    size_t off = 0;
    auto alloc = [&](size_t bytes) {
        void* p = ws + off;
        off += (bytes + 255) & ~(size_t)255;
        return p;
    };
    float* xA       = (float*)alloc(sizeof(float) * (size_t)NN * EMB_DIM); // 102.4 MB
    float* xB       = (float*)alloc(sizeof(float) * (size_t)NN * EMB_DIM); // 102.4 MB
    int*   deg      = (int*)  alloc(sizeof(int)   * NN);
    float* dis      = (float*)alloc(sizeof(float) * NN);
    int*   rp       = (int*)  alloc(sizeof(int)   * (NN + 1));
    int*   cursor   = (int*)  alloc(sizeof(int)   * NN);
    int*   csr_src  = (int*)  alloc(sizeof(int)   * NUM_EDGES);
    float* csr_coef = (float*)alloc(sizeof(float) * NUM_EDGES);
    int*   bsum     = (int*)  alloc(sizeof(int)   * 1024);

    hipMemsetAsync(deg,    0, sizeof(int) * NN, stream);
    hipMemsetAsync(cursor, 0, sizeof(int) * NN, stream);

    const int EB = (NUM_EDGES + 255) / 256;
    const int NB = (NN + 255) / 256;
    k_count<<<EB, 256, 0, stream>>>(col, deg);
    k_dis<<<NB, 256, 0, stream>>>(deg, dis);
    k_scan1<<<SCAN_NB, SCAN_B, 0, stream>>>(deg, rp, bsum);
    k_scan2<<<1, 1024, 0, stream>>>(bsum);
    k_scan3<<<SCAN_NB, SCAN_B, 0, stream>>>(rp, bsum);
    k_fill<<<EB, 256, 0, stream>>>(row, col, dis, rp, cursor, csr_src, csr_coef);

    const int LB = ((size_t)NN * 64 + 255) / 256;  // one wave (64 lanes) per node
    k_layer<0><<<LB, 256, 0, stream>>>(emb, rp, csr_src, csr_coef, xA, out);
    k_layer<1><<<LB, 256, 0, stream>>>(xA,  rp, csr_src, csr_coef, xB, out);
    k_layer<2><<<LB, 256, 0, stream>>>(xB,  rp, csr_src, csr_coef, nullptr, out);
}

// Round 2
// 339.987 us; speedup vs baseline: 1.4781x; 1.4781x over previous
//
#include <hip/hip_runtime.h>

#define NUM_USERS 100000
#define NUM_ITEMS 100000
#define EMB_DIM   128
#define NUM_EDGES 600000
#define NN        200000   // N_NODES

#define SCAN_B  256
#define SCAN_NB ((NN + SCAN_B - 1) / SCAN_B)   // 782

// ---------- degree count (in-degree over col) ----------
__global__ void k_count(const int* __restrict__ col, int* __restrict__ deg) {
    int e = blockIdx.x * blockDim.x + threadIdx.x;
    if (e < NUM_EDGES) atomicAdd(&deg[col[e]], 1);
}

// ---------- deg_inv_sqrt ----------
__global__ void k_dis(const int* __restrict__ deg, float* __restrict__ dis) {
    int i = blockIdx.x * blockDim.x + threadIdx.x;
    if (i < NN) {
        int d = deg[i];
        dis[i] = (d > 0) ? 1.0f / sqrtf((float)d) : 0.0f;
    }
}

// ---------- exclusive scan of deg -> row_ptr (3 kernels) ----------
__global__ void k_scan1(const int* __restrict__ deg, int* __restrict__ rp,
                        int* __restrict__ bsum) {
    __shared__ int s[SCAN_B];
    int tid = threadIdx.x;
    int i = blockIdx.x * SCAN_B + tid;
    int v = (i < NN) ? deg[i] : 0;
    s[tid] = v;
    __syncthreads();
    for (int off = 1; off < SCAN_B; off <<= 1) {
        int t = (tid >= off) ? s[tid - off] : 0;
        __syncthreads();
        s[tid] += t;
        __syncthreads();
    }
    if (i < NN) rp[i] = s[tid] - v;           // exclusive within block
    if (tid == SCAN_B - 1) bsum[blockIdx.x] = s[tid];
}

__global__ void k_scan2(int* __restrict__ bsum) {
    __shared__ int s[1024];
    int tid = threadIdx.x;
    int v = (tid < SCAN_NB) ? bsum[tid] : 0;
    s[tid] = v;
    __syncthreads();
    for (int off = 1; off < 1024; off <<= 1) {
        int t = (tid >= off) ? s[tid - off] : 0;
        __syncthreads();
        s[tid] += t;
        __syncthreads();
    }
    if (tid < SCAN_NB) bsum[tid] = s[tid] - v;  // exclusive
}

__global__ void k_scan3(int* __restrict__ rp, const int* __restrict__ bsum) {
    int i = blockIdx.x * SCAN_B + threadIdx.x;
    if (i < NN) rp[i] += bsum[blockIdx.x];
    if (i == 0) rp[NN] = NUM_EDGES;
}

// ---------- CSR fill (by destination node) ----------
__global__ void k_fill(const int* __restrict__ row, const int* __restrict__ col,
                       const float* __restrict__ dis, const int* __restrict__ rp,
                       int* __restrict__ cursor, int* __restrict__ csr_src,
                       float* __restrict__ csr_coef) {
    int e = blockIdx.x * blockDim.x + threadIdx.x;
    if (e >= NUM_EDGES) return;
    int r = row[e], c = col[e];
    int p = rp[c] + atomicAdd(&cursor[c], 1);
    csr_src[p]  = r;
    csr_coef[p] = dis[r] * dis[c];
}

// ---------- one propagation layer ----------
// 32 lanes per node (float4/lane); degree loop flat-unrolled x4 with clamped
// indices + zeroed coefs so all 4 index loads, then all 4 gathers, issue
// independently (breaks the src[k] -> x[src[k]] serial chain).
// MODE 0: y = A x   (x == emb);  xn = y;  out = x + y
// MODE 1: y = A x;               xn = y;  out += y
// MODE 2: y = A x;                        out = (out + y) * 0.25
template <int MODE>
__global__ void k_layer(const float* __restrict__ x, const int* __restrict__ rp,
                        const int* __restrict__ src, const float* __restrict__ coef,
                        float* __restrict__ xn, float* __restrict__ out) {
    int t    = blockIdx.x * blockDim.x + threadIdx.x;
    int node = t >> 5;               // 32 lanes per node
    int lane = t & 31;
    if (node >= NN) return;
    int beg = rp[node], end = rp[node + 1];
    float ax = 0.0f, ay = 0.0f, az = 0.0f, aw = 0.0f;
    const int bd = lane * 4;
    for (int k = beg; k < end; k += 4) {
        const int last = end - 1;
        const int k1 = min(k + 1, last);
        const int k2 = min(k + 2, last);
        const int k3 = min(k + 3, last);
        // independent index/coef loads (always in-bounds)
        const int s0 = src[k],  s1 = src[k1], s2 = src[k2], s3 = src[k3];
        float c0 = coef[k], c1 = coef[k1], c2 = coef[k2], c3 = coef[k3];
        c1 = (k + 1 <= last) ? c1 : 0.0f;
        c2 = (k + 2 <= last) ? c2 : 0.0f;
        c3 = (k + 3 <= last) ? c3 : 0.0f;
        // 4 independent gathers in flight
        const float4 v0 = *reinterpret_cast<const float4*>(x + (size_t)s0 * EMB_DIM + bd);
        const float4 v1 = *reinterpret_cast<const float4*>(x + (size_t)s1 * EMB_DIM + bd);
        const float4 v2 = *reinterpret_cast<const float4*>(x + (size_t)s2 * EMB_DIM + bd);
        const float4 v3 = *reinterpret_cast<const float4*>(x + (size_t)s3 * EMB_DIM + bd);
        ax += c0 * v0.x + c1 * v1.x + c2 * v2.x + c3 * v3.x;
        ay += c0 * v0.y + c1 * v1.y + c2 * v2.y + c3 * v3.y;
        az += c0 * v0.z + c1 * v1.z + c2 * v2.z + c3 * v3.z;
        aw += c0 * v0.w + c1 * v1.w + c2 * v2.w + c3 * v3.w;
    }
    const size_t o = (size_t)node * EMB_DIM + bd;
    if (MODE == 0) {
        *reinterpret_cast<float4*>(xn + o) = make_float4(ax, ay, az, aw);
        const float4 e = *reinterpret_cast<const float4*>(x + o);
        *reinterpret_cast<float4*>(out + o) =
            make_float4(e.x + ax, e.y + ay, e.z + az, e.w + aw);
    } else if (MODE == 1) {
        *reinterpret_cast<float4*>(xn + o) = make_float4(ax, ay, az, aw);
        const float4 t4 = *reinterpret_cast<const float4*>(out + o);
        *reinterpret_cast<float4*>(out + o) =
            make_float4(t4.x + ax, t4.y + ay, t4.z + az, t4.w + aw);
    } else {
        const float4 t4 = *reinterpret_cast<const float4*>(out + o);
        *reinterpret_cast<float4*>(out + o) =
            make_float4((t4.x + ax) * 0.25f, (t4.y + ay) * 0.25f,
                        (t4.z + az) * 0.25f, (t4.w + aw) * 0.25f);
    }
}

extern "C" void kernel_launch(void* const* d_in, const int* in_sizes, int n_in,
                              void* d_out, int out_size, void* d_ws, size_t ws_size,
                              hipStream_t stream) {
    const int*   edges = (const int*)d_in[0];
    const int*   row   = edges;               // edge_index[0]
    const int*   col   = edges + NUM_EDGES;   // edge_index[1]
    const float* emb   = (const float*)d_in[1];
    float*       out   = (float*)d_out;

    char*  ws  = (char*)d_ws;
    size_t off = 0;
    auto alloc = [&](size_t bytes) {
        void* p = ws + off;
        off += (bytes + 255) & ~(size_t)255;
        return p;
    };
    float* xA       = (float*)alloc(sizeof(float) * (size_t)NN * EMB_DIM); // 102.4 MB
    float* xB       = (float*)alloc(sizeof(float) * (size_t)NN * EMB_DIM); // 102.4 MB
    int*   deg      = (int*)  alloc(sizeof(int)   * NN);
    float* dis      = (float*)alloc(sizeof(float) * NN);
    int*   rp       = (int*)  alloc(sizeof(int)   * (NN + 1));
    int*   cursor   = (int*)  alloc(sizeof(int)   * NN);
    int*   csr_src  = (int*)  alloc(sizeof(int)   * NUM_EDGES);
    float* csr_coef = (float*)alloc(sizeof(float) * NUM_EDGES);
    int*   bsum     = (int*)  alloc(sizeof(int)   * 1024);

    hipMemsetAsync(deg,    0, sizeof(int) * NN, stream);
    hipMemsetAsync(cursor, 0, sizeof(int) * NN, stream);

    const int EB = (NUM_EDGES + 255) / 256;
    const int NB = (NN + 255) / 256;
    k_count<<<EB, 256, 0, stream>>>(col, deg);
    k_dis<<<NB, 256, 0, stream>>>(deg, dis);
    k_scan1<<<SCAN_NB, SCAN_B, 0, stream>>>(deg, rp, bsum);
    k_scan2<<<1, 1024, 0, stream>>>(bsum);
    k_scan3<<<SCAN_NB, SCAN_B, 0, stream>>>(rp, bsum);
    k_fill<<<EB, 256, 0, stream>>>(row, col, dis, rp, cursor, csr_src, csr_coef);

    const int LB = (int)(((size_t)NN * 32 + 255) / 256);  // 32 lanes per node
    k_layer<0><<<LB, 256, 0, stream>>>(emb, rp, csr_src, csr_coef, xA, out);
    k_layer<1><<<LB, 256, 0, stream>>>(xA,  rp, csr_src, csr_coef, xB, out);
    k_layer<2><<<LB, 256, 0, stream>>>(xB,  rp, csr_src, csr_coef, nullptr, out);
}

// Round 3
// 235.548 us; speedup vs baseline: 2.1335x; 1.4434x over previous
//
#include <hip/hip_runtime.h>

#define NUM_USERS 100000
#define NUM_ITEMS 100000
#define EMB_DIM   128
#define NUM_EDGES 600000
#define NN        200000   // N_NODES

#define SCAN_B  256
#define SCAN_NB ((NN + SCAN_B - 1) / SCAN_B)   // 782

// bf16 helpers (RNE rounding)
__device__ inline float bf2f(unsigned short u) {
    unsigned int x = ((unsigned int)u) << 16;
    return __builtin_bit_cast(float, x);
}
__device__ inline unsigned short f2bf(float f) {
    unsigned int x = __builtin_bit_cast(unsigned int, f);
    x += 0x7fffu + ((x >> 16) & 1u);   // round-to-nearest-even
    return (unsigned short)(x >> 16);
}

// ---------- degree count (in-degree over col) ----------
__global__ void k_count(const int* __restrict__ col, int* __restrict__ deg) {
    int e = blockIdx.x * blockDim.x + threadIdx.x;
    if (e < NUM_EDGES) atomicAdd(&deg[col[e]], 1);
}

// ---------- deg_inv_sqrt ----------
__global__ void k_dis(const int* __restrict__ deg, float* __restrict__ dis) {
    int i = blockIdx.x * blockDim.x + threadIdx.x;
    if (i < NN) {
        int d = deg[i];
        dis[i] = (d > 0) ? 1.0f / sqrtf((float)d) : 0.0f;
    }
}

// ---------- exclusive scan of deg -> row_ptr (3 kernels) ----------
__global__ void k_scan1(const int* __restrict__ deg, int* __restrict__ rp,
                        int* __restrict__ bsum) {
    __shared__ int s[SCAN_B];
    int tid = threadIdx.x;
    int i = blockIdx.x * SCAN_B + tid;
    int v = (i < NN) ? deg[i] : 0;
    s[tid] = v;
    __syncthreads();
    for (int off = 1; off < SCAN_B; off <<= 1) {
        int t = (tid >= off) ? s[tid - off] : 0;
        __syncthreads();
        s[tid] += t;
        __syncthreads();
    }
    if (i < NN) rp[i] = s[tid] - v;
    if (tid == SCAN_B - 1) bsum[blockIdx.x] = s[tid];
}

__global__ void k_scan2(int* __restrict__ bsum) {
    __shared__ int s[1024];
    int tid = threadIdx.x;
    int v = (tid < SCAN_NB) ? bsum[tid] : 0;
    s[tid] = v;
    __syncthreads();
    for (int off = 1; off < 1024; off <<= 1) {
        int t = (tid >= off) ? s[tid - off] : 0;
        __syncthreads();
        s[tid] += t;
        __syncthreads();
    }
    if (tid < SCAN_NB) bsum[tid] = s[tid] - v;
}

__global__ void k_scan3(int* __restrict__ rp, const int* __restrict__ bsum) {
    int i = blockIdx.x * SCAN_B + threadIdx.x;
    if (i < NN) rp[i] += bsum[blockIdx.x];
    if (i == 0) rp[NN] = NUM_EDGES;
}

// ---------- CSR fill (by destination node) ----------
__global__ void k_fill(const int* __restrict__ row, const int* __restrict__ col,
                       const float* __restrict__ dis, const int* __restrict__ rp,
                       int* __restrict__ cursor, int* __restrict__ csr_src,
                       float* __restrict__ csr_coef) {
    int e = blockIdx.x * blockDim.x + threadIdx.x;
    if (e >= NUM_EDGES) return;
    int r = row[e], c = col[e];
    int p = rp[c] + atomicAdd(&cursor[c], 1);
    csr_src[p]  = r;
    csr_coef[p] = dis[r] * dis[c];
}

// ---------- layer 0: y1 = A * emb(f32), store y1 as bf16 ----------
__global__ void k_layer0(const float* __restrict__ x, const int* __restrict__ rp,
                         const int* __restrict__ src, const float* __restrict__ coef,
                         ushort* __restrict__ xn) {
    int t    = blockIdx.x * blockDim.x + threadIdx.x;
    int node = t >> 5;
    int lane = t & 31;
    if (node >= NN) return;
    int beg = rp[node], end = rp[node + 1];
    float a0 = 0, a1 = 0, a2 = 0, a3 = 0;
    const int bd = lane * 4;
    for (int k = beg; k < end; k += 4) {
        const int last = end - 1;
        const int k1 = min(k + 1, last), k2 = min(k + 2, last), k3 = min(k + 3, last);
        const int s0 = src[k], s1 = src[k1], s2 = src[k2], s3 = src[k3];
        float c0 = coef[k], c1 = coef[k1], c2 = coef[k2], c3 = coef[k3];
        c1 = (k + 1 <= last) ? c1 : 0.0f;
        c2 = (k + 2 <= last) ? c2 : 0.0f;
        c3 = (k + 3 <= last) ? c3 : 0.0f;
        const float4 v0 = *reinterpret_cast<const float4*>(x + (size_t)s0 * EMB_DIM + bd);
        const float4 v1 = *reinterpret_cast<const float4*>(x + (size_t)s1 * EMB_DIM + bd);
        const float4 v2 = *reinterpret_cast<const float4*>(x + (size_t)s2 * EMB_DIM + bd);
        const float4 v3 = *reinterpret_cast<const float4*>(x + (size_t)s3 * EMB_DIM + bd);
        a0 += c0 * v0.x + c1 * v1.x + c2 * v2.x + c3 * v3.x;
        a1 += c0 * v0.y + c1 * v1.y + c2 * v2.y + c3 * v3.y;
        a2 += c0 * v0.z + c1 * v1.z + c2 * v2.z + c3 * v3.z;
        a3 += c0 * v0.w + c1 * v1.w + c2 * v2.w + c3 * v3.w;
    }
    ushort4 w;
    w.x = f2bf(a0); w.y = f2bf(a1); w.z = f2bf(a2); w.w = f2bf(a3);
    *reinterpret_cast<ushort4*>(xn + (size_t)node * EMB_DIM + bd) = w;
}

// ---------- layer 1: y2 = A * x1(bf16), store bf16 ----------
// ---------- layer 2 (FINAL=1): y3 = A * x2(bf16);
//            out = (emb + x1 + x2 + y3) * 0.25 ----------
template <int FINAL>
__global__ void k_layerb(const ushort* __restrict__ x, const int* __restrict__ rp,
                         const int* __restrict__ src, const float* __restrict__ coef,
                         ushort* __restrict__ xn,
                         const float* __restrict__ emb, const ushort* __restrict__ x1,
                         float* __restrict__ out) {
    int t    = blockIdx.x * blockDim.x + threadIdx.x;
    int node = t >> 5;
    int lane = t & 31;
    if (node >= NN) return;
    int beg = rp[node], end = rp[node + 1];
    float a0 = 0, a1 = 0, a2 = 0, a3 = 0;
    const int bd = lane * 4;
    for (int k = beg; k < end; k += 4) {
        const int last = end - 1;
        const int k1 = min(k + 1, last), k2 = min(k + 2, last), k3 = min(k + 3, last);
        const int s0 = src[k], s1 = src[k1], s2 = src[k2], s3 = src[k3];
        float c0 = coef[k], c1 = coef[k1], c2 = coef[k2], c3 = coef[k3];
        c1 = (k + 1 <= last) ? c1 : 0.0f;
        c2 = (k + 2 <= last) ? c2 : 0.0f;
        c3 = (k + 3 <= last) ? c3 : 0.0f;
        const ushort4 u0 = *reinterpret_cast<const ushort4*>(x + (size_t)s0 * EMB_DIM + bd);
        const ushort4 u1 = *reinterpret_cast<const ushort4*>(x + (size_t)s1 * EMB_DIM + bd);
        const ushort4 u2 = *reinterpret_cast<const ushort4*>(x + (size_t)s2 * EMB_DIM + bd);
        const ushort4 u3 = *reinterpret_cast<const ushort4*>(x + (size_t)s3 * EMB_DIM + bd);
        a0 += c0 * bf2f(u0.x) + c1 * bf2f(u1.x) + c2 * bf2f(u2.x) + c3 * bf2f(u3.x);
        a1 += c0 * bf2f(u0.y) + c1 * bf2f(u1.y) + c2 * bf2f(u2.y) + c3 * bf2f(u3.y);
        a2 += c0 * bf2f(u0.z) + c1 * bf2f(u1.z) + c2 * bf2f(u2.z) + c3 * bf2f(u3.z);
        a3 += c0 * bf2f(u0.w) + c1 * bf2f(u1.w) + c2 * bf2f(u2.w) + c3 * bf2f(u3.w);
    }
    const size_t o = (size_t)node * EMB_DIM + bd;
    if (FINAL == 0) {
        ushort4 w;
        w.x = f2bf(a0); w.y = f2bf(a1); w.z = f2bf(a2); w.w = f2bf(a3);
        *reinterpret_cast<ushort4*>(xn + o) = w;
    } else {
        const float4  e  = *reinterpret_cast<const float4*>(emb + o);
        const ushort4 w1 = *reinterpret_cast<const ushort4*>(x1 + o);
        const ushort4 w2 = *reinterpret_cast<const ushort4*>(x + o);   // x == x2
        float4 r;
        r.x = (e.x + bf2f(w1.x) + bf2f(w2.x) + a0) * 0.25f;
        r.y = (e.y + bf2f(w1.y) + bf2f(w2.y) + a1) * 0.25f;
        r.z = (e.z + bf2f(w1.z) + bf2f(w2.z) + a2) * 0.25f;
        r.w = (e.w + bf2f(w1.w) + bf2f(w2.w) + a3) * 0.25f;
        *reinterpret_cast<float4*>(out + o) = r;
    }
}

extern "C" void kernel_launch(void* const* d_in, const int* in_sizes, int n_in,
                              void* d_out, int out_size, void* d_ws, size_t ws_size,
                              hipStream_t stream) {
    const int*   edges = (const int*)d_in[0];
    const int*   row   = edges;               // edge_index[0]
    const int*   col   = edges + NUM_EDGES;   // edge_index[1]
    const float* emb   = (const float*)d_in[1];
    float*       out   = (float*)d_out;

    char*  ws  = (char*)d_ws;
    size_t off = 0;
    auto alloc = [&](size_t bytes) {
        void* p = ws + off;
        off += (bytes + 255) & ~(size_t)255;
        return p;
    };
    ushort* x1       = (ushort*)alloc(sizeof(ushort) * (size_t)NN * EMB_DIM); // 51.2 MB
    ushort* x2       = (ushort*)alloc(sizeof(ushort) * (size_t)NN * EMB_DIM); // 51.2 MB
    int*    deg      = (int*)   alloc(sizeof(int)   * NN);
    float*  dis      = (float*) alloc(sizeof(float) * NN);
    int*    rp       = (int*)   alloc(sizeof(int)   * (NN + 1));
    int*    cursor   = (int*)   alloc(sizeof(int)   * NN);
    int*    csr_src  = (int*)   alloc(sizeof(int)   * NUM_EDGES);
    float*  csr_coef = (float*) alloc(sizeof(float) * NUM_EDGES);
    int*    bsum     = (int*)   alloc(sizeof(int)   * 1024);

    hipMemsetAsync(deg,    0, sizeof(int) * NN, stream);
    hipMemsetAsync(cursor, 0, sizeof(int) * NN, stream);

    const int EB = (NUM_EDGES + 255) / 256;
    const int NB = (NN + 255) / 256;
    k_count<<<EB, 256, 0, stream>>>(col, deg);
    k_dis<<<NB, 256, 0, stream>>>(deg, dis);
    k_scan1<<<SCAN_NB, SCAN_B, 0, stream>>>(deg, rp, bsum);
    k_scan2<<<1, 1024, 0, stream>>>(bsum);
    k_scan3<<<SCAN_NB, SCAN_B, 0, stream>>>(rp, bsum);
    k_fill<<<EB, 256, 0, stream>>>(row, col, dis, rp, cursor, csr_src, csr_coef);

    const int LB = (int)(((size_t)NN * 32 + 255) / 256);  // 32 lanes per node
    k_layer0<<<LB, 256, 0, stream>>>(emb, rp, csr_src, csr_coef, x1);
    k_layerb<0><<<LB, 256, 0, stream>>>(x1, rp, csr_src, csr_coef, x2,
                                        nullptr, nullptr, nullptr);
    k_layerb<1><<<LB, 256, 0, stream>>>(x2, rp, csr_src, csr_coef, nullptr,
                                        emb, x1, out);
}

// Round 5
// 220.574 us; speedup vs baseline: 2.2783x; 1.0679x over previous
//
#include <hip/hip_runtime.h>

#define NUM_USERS 100000
#define NUM_ITEMS 100000
#define EMB_DIM   128
#define NUM_EDGES 600000
#define NN        200000   // N_NODES

#define SCAN_B  256
#define SCAN_NB ((NN + SCAN_B - 1) / SCAN_B)   // 782

typedef __attribute__((ext_vector_type(8))) unsigned short ushort8_t;
typedef __attribute__((ext_vector_type(4))) float float4_t;

// bf16 helpers (RNE rounding)
__device__ inline float bf2f(unsigned short u) {
    unsigned int x = ((unsigned int)u) << 16;
    return __builtin_bit_cast(float, x);
}
__device__ inline unsigned short f2bf(float f) {
    unsigned int x = __builtin_bit_cast(unsigned int, f);
    x += 0x7fffu + ((x >> 16) & 1u);   // round-to-nearest-even
    return (unsigned short)(x >> 16);
}

// ---------- emb f32 -> x0 bf16 (one-time, streaming) ----------
__global__ void k_conv(const float* __restrict__ emb, ushort* __restrict__ x0) {
    int i = blockIdx.x * blockDim.x + threadIdx.x;   // over NN*EMB_DIM/4
    const float4 v = reinterpret_cast<const float4*>(emb)[i];
    ushort4 w;
    w.x = f2bf(v.x); w.y = f2bf(v.y); w.z = f2bf(v.z); w.w = f2bf(v.w);
    reinterpret_cast<ushort4*>(x0)[i] = w;
}

// ---------- degree count (in-degree over col) ----------
__global__ void k_count(const int* __restrict__ col, int* __restrict__ deg) {
    int e = blockIdx.x * blockDim.x + threadIdx.x;
    if (e < NUM_EDGES) atomicAdd(&deg[col[e]], 1);
}

// ---------- scan part 1 + deg_inv_sqrt fused ----------
__global__ void k_scan1(const int* __restrict__ deg, int* __restrict__ rp,
                        int* __restrict__ bsum, float* __restrict__ dis) {
    __shared__ int s[SCAN_B];
    int tid = threadIdx.x;
    int i = blockIdx.x * SCAN_B + tid;
    int v = (i < NN) ? deg[i] : 0;
    s[tid] = v;
    __syncthreads();
    for (int off = 1; off < SCAN_B; off <<= 1) {
        int t = (tid >= off) ? s[tid - off] : 0;
        __syncthreads();
        s[tid] += t;
        __syncthreads();
    }
    if (i < NN) {
        rp[i]  = s[tid] - v;                    // exclusive within block
        dis[i] = (v > 0) ? 1.0f / sqrtf((float)v) : 0.0f;
    }
    if (tid == SCAN_B - 1) bsum[blockIdx.x] = s[tid];
}

__global__ void k_scan2(int* __restrict__ bsum) {
    __shared__ int s[1024];
    int tid = threadIdx.x;
    int v = (tid < SCAN_NB) ? bsum[tid] : 0;
    s[tid] = v;
    __syncthreads();
    for (int off = 1; off < 1024; off <<= 1) {
        int t = (tid >= off) ? s[tid - off] : 0;
        __syncthreads();
        s[tid] += t;
        __syncthreads();
    }
    if (tid < SCAN_NB) bsum[tid] = s[tid] - v;
}

__global__ void k_scan3(int* __restrict__ rp, const int* __restrict__ bsum) {
    int i = blockIdx.x * SCAN_B + threadIdx.x;
    if (i < NN) rp[i] += bsum[blockIdx.x];
    if (i == 0) rp[NN] = NUM_EDGES;
}

// ---------- CSR fill, packed (src, coef) ----------
__global__ void k_fill(const int* __restrict__ row, const int* __restrict__ col,
                       const float* __restrict__ dis, const int* __restrict__ rp,
                       int* __restrict__ cursor, int2* __restrict__ csr) {
    int e = blockIdx.x * blockDim.x + threadIdx.x;
    if (e >= NUM_EDGES) return;
    int r = row[e], c = col[e];
    int p = rp[c] + atomicAdd(&cursor[c], 1);
    csr[p] = make_int2(r, __builtin_bit_cast(int, dis[r] * dis[c]));
}

// ---------- propagation layer: y = A * x (bf16), store bf16 ----------
// 16 lanes per node, ushort8 (16B) per lane; degree loop flat-unrolled x4.
__global__ void k_gath(const ushort* __restrict__ x, const int* __restrict__ rp,
                       const int2* __restrict__ csr, ushort* __restrict__ xn) {
    int t    = blockIdx.x * blockDim.x + threadIdx.x;
    int node = t >> 4;
    int lane = t & 15;
    if (node >= NN) return;
    int beg = rp[node], end = rp[node + 1];
    float a[8] = {0, 0, 0, 0, 0, 0, 0, 0};
    const int bd = lane * 8;
    for (int k = beg; k < end; k += 4) {
        const int last = end - 1;
        const int k1 = min(k + 1, last), k2 = min(k + 2, last), k3 = min(k + 3, last);
        const int2 e0 = csr[k], e1 = csr[k1], e2 = csr[k2], e3 = csr[k3];
        const float c0 = __builtin_bit_cast(float, e0.y);
        const float c1 = (k + 1 <= last) ? __builtin_bit_cast(float, e1.y) : 0.0f;
        const float c2 = (k + 2 <= last) ? __builtin_bit_cast(float, e2.y) : 0.0f;
        const float c3 = (k + 3 <= last) ? __builtin_bit_cast(float, e3.y) : 0.0f;
        const ushort8_t v0 = *reinterpret_cast<const ushort8_t*>(x + (size_t)e0.x * EMB_DIM + bd);
        const ushort8_t v1 = *reinterpret_cast<const ushort8_t*>(x + (size_t)e1.x * EMB_DIM + bd);
        const ushort8_t v2 = *reinterpret_cast<const ushort8_t*>(x + (size_t)e2.x * EMB_DIM + bd);
        const ushort8_t v3 = *reinterpret_cast<const ushort8_t*>(x + (size_t)e3.x * EMB_DIM + bd);
#pragma unroll
        for (int j = 0; j < 8; ++j)
            a[j] += c0 * bf2f(v0[j]) + c1 * bf2f(v1[j]) +
                    c2 * bf2f(v2[j]) + c3 * bf2f(v3[j]);
    }
    ushort8_t w;
#pragma unroll
    for (int j = 0; j < 8; ++j) w[j] = f2bf(a[j]);
    *reinterpret_cast<ushort8_t*>(xn + (size_t)node * EMB_DIM + bd) = w;
}

// ---------- final layer: y3 = A * x2;  out = (x0 + x1 + x2 + y3) * 0.25 ----------
__global__ void k_final(const ushort* __restrict__ x2, const int* __restrict__ rp,
                        const int2* __restrict__ csr,
                        const ushort* __restrict__ x0, const ushort* __restrict__ x1,
                        float* __restrict__ out) {
    int t    = blockIdx.x * blockDim.x + threadIdx.x;
    int node = t >> 4;
    int lane = t & 15;
    if (node >= NN) return;
    int beg = rp[node], end = rp[node + 1];
    float a[8] = {0, 0, 0, 0, 0, 0, 0, 0};
    const int bd = lane * 8;
    for (int k = beg; k < end; k += 4) {
        const int last = end - 1;
        const int k1 = min(k + 1, last), k2 = min(k + 2, last), k3 = min(k + 3, last);
        const int2 e0 = csr[k], e1 = csr[k1], e2 = csr[k2], e3 = csr[k3];
        const float c0 = __builtin_bit_cast(float, e0.y);
        const float c1 = (k + 1 <= last) ? __builtin_bit_cast(float, e1.y) : 0.0f;
        const float c2 = (k + 2 <= last) ? __builtin_bit_cast(float, e2.y) : 0.0f;
        const float c3 = (k + 3 <= last) ? __builtin_bit_cast(float, e3.y) : 0.0f;
        const ushort8_t v0 = *reinterpret_cast<const ushort8_t*>(x2 + (size_t)e0.x * EMB_DIM + bd);
        const ushort8_t v1 = *reinterpret_cast<const ushort8_t*>(x2 + (size_t)e1.x * EMB_DIM + bd);
        const ushort8_t v2 = *reinterpret_cast<const ushort8_t*>(x2 + (size_t)e2.x * EMB_DIM + bd);
        const ushort8_t v3 = *reinterpret_cast<const ushort8_t*>(x2 + (size_t)e3.x * EMB_DIM + bd);
#pragma unroll
        for (int j = 0; j < 8; ++j)
            a[j] += c0 * bf2f(v0[j]) + c1 * bf2f(v1[j]) +
                    c2 * bf2f(v2[j]) + c3 * bf2f(v3[j]);
    }
    const size_t o = (size_t)node * EMB_DIM + bd;
    const ushort8_t w0 = *reinterpret_cast<const ushort8_t*>(x0 + o);
    const ushort8_t w1 = *reinterpret_cast<const ushort8_t*>(x1 + o);
    const ushort8_t w2 = *reinterpret_cast<const ushort8_t*>(x2 + o);
    float4_t r0, r1;
#pragma unroll
    for (int j = 0; j < 4; ++j)
        r0[j] = (bf2f(w0[j]) + bf2f(w1[j]) + bf2f(w2[j]) + a[j]) * 0.25f;
#pragma unroll
    for (int j = 0; j < 4; ++j)
        r1[j] = (bf2f(w0[j + 4]) + bf2f(w1[j + 4]) + bf2f(w2[j + 4]) + a[j + 4]) * 0.25f;
    // out is never re-read: nontemporal keeps x0/x1/x2 L3-resident for the gather
    __builtin_nontemporal_store(r0, reinterpret_cast<float4_t*>(out + o));
    __builtin_nontemporal_store(r1, reinterpret_cast<float4_t*>(out + o) + 1);
}

extern "C" void kernel_launch(void* const* d_in, const int* in_sizes, int n_in,
                              void* d_out, int out_size, void* d_ws, size_t ws_size,
                              hipStream_t stream) {
    const int*   edges = (const int*)d_in[0];
    const int*   row   = edges;               // edge_index[0]
    const int*   col   = edges + NUM_EDGES;   // edge_index[1]
    const float* emb   = (const float*)d_in[1];
    float*       out   = (float*)d_out;

    char*  ws  = (char*)d_ws;
    size_t off = 0;
    auto alloc = [&](size_t bytes) {
        void* p = ws + off;
        off += (bytes + 255) & ~(size_t)255;
        return p;
    };
    ushort* x0     = (ushort*)alloc(sizeof(ushort) * (size_t)NN * EMB_DIM); // 51.2 MB
    ushort* x1     = (ushort*)alloc(sizeof(ushort) * (size_t)NN * EMB_DIM); // 51.2 MB
    ushort* x2     = (ushort*)alloc(sizeof(ushort) * (size_t)NN * EMB_DIM); // 51.2 MB
    int*    deg    = (int*)   alloc(sizeof(int)   * NN);
    float*  dis    = (float*) alloc(sizeof(float) * NN);
    int*    rp     = (int*)   alloc(sizeof(int)   * (NN + 1));
    int*    cursor = (int*)   alloc(sizeof(int)   * NN);
    int2*   csr    = (int2*)  alloc(sizeof(int2)  * NUM_EDGES);             // 4.8 MB
    int*    bsum   = (int*)   alloc(sizeof(int)   * 1024);

    (void)hipMemsetAsync(deg,    0, sizeof(int) * NN, stream);
    (void)hipMemsetAsync(cursor, 0, sizeof(int) * NN, stream);

    const int EB = (NUM_EDGES + 255) / 256;
    const int CB = (int)(((size_t)NN * EMB_DIM / 4) / 256);   // 25000
    k_conv<<<CB, 256, 0, stream>>>(emb, x0);
    k_count<<<EB, 256, 0, stream>>>(col, deg);
    k_scan1<<<SCAN_NB, SCAN_B, 0, stream>>>(deg, rp, bsum, dis);
    k_scan2<<<1, 1024, 0, stream>>>(bsum);
    k_scan3<<<SCAN_NB, SCAN_B, 0, stream>>>(rp, bsum);
    k_fill<<<EB, 256, 0, stream>>>(row, col, dis, rp, cursor, csr);

    const int LB = (int)(((size_t)NN * 16) / 256);            // 12500
    k_gath <<<LB, 256, 0, stream>>>(x0, rp, csr, x1);
    k_gath <<<LB, 256, 0, stream>>>(x1, rp, csr, x2);
    k_final<<<LB, 256, 0, stream>>>(x2, rp, csr, x0, x1, out);
}